// Round 4
// baseline (466.452 us; speedup 1.0000x reference)
//
#include <hip/hip_runtime.h>

#define C_DIM 2048
#define T_TOKENS 4096

typedef float v4f __attribute__((ext_vector_type(4)));

// Fused: wave-per-token GEMV scores + last-block-per-batch election runs the
// variable-k top-k radix selection for that batch. Election counters in d_ws,
// zeroed each call by hipMemsetAsync (graph-capturable).
__global__ __launch_bounds__(256) void fused_kernel(
    const float* __restrict__ hidden, const float* __restrict__ keep_ratio,
    const float* __restrict__ W, const float* __restrict__ bptr,
    float* __restrict__ mask_out, float* __restrict__ scores_out,
    int* __restrict__ counters, int blocks_per_batch) {
  const int tid = threadIdx.x;
  const int lane = tid & 63;
  const int wv = tid >> 6;
  const int token = blockIdx.x * 4 + wv;
  const int b = token >> 12;  // token / 4096

  // ---- Phase 1: score[token] = dot(hidden[token,:], W) + b0 ----
  // f64 accumulation: scores ~exact so the top-k boundary ordering matches
  // the np reference (validated rounds 0-2 -- do not perturb).
  {
    const float* row = hidden + (size_t)token * C_DIM;
    double acc = 0.0;
#pragma unroll
    for (int it = 0; it < C_DIM / (64 * 4); ++it) {
      int c = it * 256 + lane * 4;
      v4f h = __builtin_nontemporal_load(
          reinterpret_cast<const v4f*>(row + c));  // single-use stream: nt
      float4 w = *reinterpret_cast<const float4*>(W + c);
      acc += (double)h.x * (double)w.x;
      acc += (double)h.y * (double)w.y;
      acc += (double)h.z * (double)w.z;
      acc += (double)h.w * (double)w.w;
    }
    for (int o = 32; o; o >>= 1) acc += __shfl_xor(acc, o);
    if (lane == 0) scores_out[token] = (float)(acc + (double)bptr[0]);
  }

  // ---- Election: last-arriving block of batch b runs the top-k ----
  __shared__ int s_elect;
  __syncthreads();  // compiler drains vmcnt(0) before s_barrier: stores done
  if (tid == 0) {
    __threadfence();  // release: batch-b scores device-visible before count
    int old = atomicAdd(&counters[b], 1);
    s_elect = (old == blocks_per_batch - 1) ? 1 : 0;
  }
  __syncthreads();
  if (!s_elect) return;
  __threadfence();  // acquire: observe every block's score stores

  // ---- Phase 2: variable-k top-k mask for batch b (radix descent) ----
  const float* scores = scores_out + (size_t)b * T_TOKENS;
  __shared__ int s_hist[256];
  __shared__ int s_wave[4];
  __shared__ unsigned int s_sel;
  __shared__ int s_krem;

  // k = max(1, trunc(clip(kr, 0.1, 1.0) * T)); *4096 is a pure exponent
  // shift in fp32 -> exact, truncation matches jnp int32 cast bit-for-bit.
  float kf = fminf(fmaxf(keep_ratio[b], 0.1f), 1.0f);
  int k = (int)(kf * (float)T_TOKENS);
  if (k < 1) k = 1;

  // Thread tid owns tokens [tid*16, tid*16+16) -> order-preserving uint keys.
  unsigned int key[16];
  const float* base = scores + tid * 16;
#pragma unroll
  for (int i = 0; i < 16; i += 4) {
    float4 s4 = *reinterpret_cast<const float4*>(base + i);
    float ss[4] = {s4.x, s4.y, s4.z, s4.w};
#pragma unroll
    for (int j = 0; j < 4; ++j) {
      unsigned int u = __float_as_uint(ss[j]);
      key[i + j] = (u & 0x80000000u) ? ~u : (u | 0x80000000u);
    }
  }

  // 4-round byte radix descent: after round r, prefix = top (r+1) bytes of
  // the k-th largest key; krem = remaining quota within that prefix.
  unsigned int prefix = 0u;
  int krem = k;
#pragma unroll
  for (int round = 0; round < 4; ++round) {
    const int shift = 24 - 8 * round;
    const unsigned int pmask = (round == 0) ? 0u : (0xFFFFFFFFu << (shift + 8));

    s_hist[tid] = 0;
    __syncthreads();
#pragma unroll
    for (int i = 0; i < 16; ++i) {
      if ((key[i] & pmask) == prefix)
        atomicAdd(&s_hist[(key[i] >> shift) & 255], 1);
    }
    __syncthreads();

    // Inclusive suffix sum over 256 bins (bin index == tid).
    int v = s_hist[tid];
    int x = v;
#pragma unroll
    for (int off = 1; off < 64; off <<= 1) {
      int y = __shfl_down(x, off);
      if (lane + off < 64) x += y;
    }
    if (lane == 0) s_wave[wv] = x;
    __syncthreads();
    int add = 0;
    for (int w = wv + 1; w < 4; ++w) add += s_wave[w];
    const int suffix_incl = x + add;         // active keys in bins >= tid
    const int suffix_excl = suffix_incl - v; // bins > tid
    if (suffix_excl < krem && suffix_incl >= krem) {  // unique crossing bin
      s_sel = (unsigned int)tid;
      s_krem = krem - suffix_excl;
    }
    __syncthreads();
    prefix |= (s_sel << shift);
    krem = s_krem;
    __syncthreads();
  }
  // prefix = key of k-th largest; krem = # ties (by index order) to keep.

  // Stable tie-break: exclusive count of equal keys at smaller token index.
  int cnt = 0;
#pragma unroll
  for (int i = 0; i < 16; ++i) cnt += (key[i] == prefix) ? 1 : 0;
  int inc = cnt;
#pragma unroll
  for (int off = 1; off < 64; off <<= 1) {
    int y = __shfl_up(inc, off);
    if (lane >= off) inc += y;
  }
  if (lane == 63) s_wave[wv] = inc;
  __syncthreads();
  int waveoff = 0;
  for (int w = 0; w < wv; ++w) waveoff += s_wave[w];
  int run = waveoff + inc - cnt;  // equal keys strictly before my first token

  float* mrow = mask_out + (size_t)b * T_TOKENS + tid * 16;
#pragma unroll
  for (int i = 0; i < 16; i += 4) {
    float4 m4;
    float mv[4];
#pragma unroll
    for (int j = 0; j < 4; ++j) {
      unsigned int kk = key[i + j];
      bool keep = (kk > prefix) || (kk == prefix && run < krem);
      run += (kk == prefix) ? 1 : 0;
      mv[j] = keep ? 1.0f : 0.0f;
    }
    m4.x = mv[0]; m4.y = mv[1]; m4.z = mv[2]; m4.w = mv[3];
    *reinterpret_cast<float4*>(mrow + i) = m4;
  }
}

extern "C" void kernel_launch(void* const* d_in, const int* in_sizes, int n_in,
                              void* d_out, int out_size, void* d_ws, size_t ws_size,
                              hipStream_t stream) {
  const float* hidden = (const float*)d_in[0];
  const float* keep_ratio = (const float*)d_in[1];
  const float* W = (const float*)d_in[2];
  const float* bptr = (const float*)d_in[3];

  const int B = in_sizes[1];
  const int n_tokens = in_sizes[0] / C_DIM;  // B*T = 32768

  float* out = (float*)d_out;
  float* mask = out;                       // output 0: [B, T] mask as 0/1 float
  float* scores = out + (size_t)n_tokens;  // output 1: [B, T] fp32 scores

  int* counters = (int*)d_ws;
  (void)hipMemsetAsync(counters, 0, (size_t)B * sizeof(int), stream);

  const int blocks = n_tokens / 4;  // 4 tokens (waves) per block
  fused_kernel<<<blocks, 256, 0, stream>>>(hidden, keep_ratio, W, bptr, mask,
                                           scores, counters, blocks / B);
}

// Round 5
// 53.166 us; speedup vs baseline: 8.7735x; 8.7735x over previous
//
#include <hip/hip_runtime.h>

#define C_DIM 2048
#define T_TOKENS 4096

typedef float v4f __attribute__((ext_vector_type(4)));

// Kernel 1: scores[n] = dot(hidden[n, :], W) + b0. Two tokens per wave:
// 16 independent 16B loads in flight per iteration (latency hiding), one
// reduce+store pair per wave. f64 accumulation: scores ~exact, so the top-k
// boundary ordering matches the np reference (validated r0-r2 -- keep).
__global__ __launch_bounds__(256) void score_kernel(
    const float* __restrict__ hidden, const float* __restrict__ W,
    const float* __restrict__ bptr, float* __restrict__ scores) {
  const int wave = (int)((blockIdx.x * blockDim.x + threadIdx.x) >> 6);
  const int lane = threadIdx.x & 63;
  const int t0 = wave * 2;
  const float* row0 = hidden + (size_t)t0 * C_DIM;
  const float* row1 = row0 + C_DIM;
  double a0 = 0.0, a1 = 0.0;
#pragma unroll
  for (int it = 0; it < C_DIM / (64 * 4); ++it) {
    const int c = it * 256 + lane * 4;
    v4f w = *reinterpret_cast<const v4f*>(W + c);
    v4f h0 = *reinterpret_cast<const v4f*>(row0 + c);
    v4f h1 = *reinterpret_cast<const v4f*>(row1 + c);
    a0 += (double)h0.x * (double)w.x;
    a0 += (double)h0.y * (double)w.y;
    a0 += (double)h0.z * (double)w.z;
    a0 += (double)h0.w * (double)w.w;
    a1 += (double)h1.x * (double)w.x;
    a1 += (double)h1.y * (double)w.y;
    a1 += (double)h1.z * (double)w.z;
    a1 += (double)h1.w * (double)w.w;
  }
  for (int o = 32; o; o >>= 1) {
    a0 += __shfl_xor(a0, o);
    a1 += __shfl_xor(a1, o);
  }
  if (lane == 0) {
    const double bb = (double)bptr[0];
    float2 s2 = make_float2((float)(a0 + bb), (float)(a1 + bb));
    *reinterpret_cast<float2*>(scores + t0) = s2;
  }
}

// Kernel 2: per-batch variable-k top-k mask via 8-bit radix histogram descent
// (validated round 2, unchanged). Thread tid owns tokens [tid*16, tid*16+16);
// stable tie-break (smaller index first) matches argsort(argsort) rank.
__global__ __launch_bounds__(256) void topk_mask_kernel(
    const float* __restrict__ keep_ratio, const float* __restrict__ scores_all,
    float* __restrict__ mask) {
  const int b = blockIdx.x;
  const float* scores = scores_all + (size_t)b * T_TOKENS;
  __shared__ int s_hist[256];
  __shared__ int s_wave[4];
  __shared__ unsigned int s_sel;
  __shared__ int s_krem;
  const int tid = threadIdx.x;
  const int lane = tid & 63;
  const int wv = tid >> 6;

  // k = max(1, trunc(clip(kr, 0.1, 1.0) * T)); *4096 is a pure exponent
  // shift in fp32 -> exact, truncation matches jnp int32 cast bit-for-bit.
  float kf = fminf(fmaxf(keep_ratio[b], 0.1f), 1.0f);
  int k = (int)(kf * (float)T_TOKENS);
  if (k < 1) k = 1;

  // Load 16 contiguous scores -> order-preserving uint keys.
  unsigned int key[16];
  const float* base = scores + tid * 16;
#pragma unroll
  for (int i = 0; i < 16; i += 4) {
    float4 s4 = *reinterpret_cast<const float4*>(base + i);
    float ss[4] = {s4.x, s4.y, s4.z, s4.w};
#pragma unroll
    for (int j = 0; j < 4; ++j) {
      unsigned int u = __float_as_uint(ss[j]);
      key[i + j] = (u & 0x80000000u) ? ~u : (u | 0x80000000u);
    }
  }

  // 4-round byte radix descent: after round r, prefix = top (r+1) bytes of
  // the k-th largest key; krem = remaining quota within that prefix.
  unsigned int prefix = 0u;
  int krem = k;
#pragma unroll
  for (int round = 0; round < 4; ++round) {
    const int shift = 24 - 8 * round;
    const unsigned int pmask = (round == 0) ? 0u : (0xFFFFFFFFu << (shift + 8));

    s_hist[tid] = 0;
    __syncthreads();
#pragma unroll
    for (int i = 0; i < 16; ++i) {
      if ((key[i] & pmask) == prefix)
        atomicAdd(&s_hist[(key[i] >> shift) & 255], 1);
    }
    __syncthreads();

    // Inclusive suffix sum over 256 bins (bin index == tid).
    int v = s_hist[tid];
    int x = v;
#pragma unroll
    for (int off = 1; off < 64; off <<= 1) {
      int y = __shfl_down(x, off);
      if (lane + off < 64) x += y;
    }
    if (lane == 0) s_wave[wv] = x;
    __syncthreads();
    int add = 0;
    for (int w = wv + 1; w < 4; ++w) add += s_wave[w];
    const int suffix_incl = x + add;         // active keys in bins >= tid
    const int suffix_excl = suffix_incl - v; // bins > tid
    if (suffix_excl < krem && suffix_incl >= krem) {  // unique crossing bin
      s_sel = (unsigned int)tid;
      s_krem = krem - suffix_excl;
    }
    __syncthreads();
    prefix |= (s_sel << shift);
    krem = s_krem;
    __syncthreads();
  }
  // prefix = key of k-th largest; krem = # ties (by index order) to keep.

  // Stable tie-break: exclusive count of equal keys at smaller token index.
  int cnt = 0;
#pragma unroll
  for (int i = 0; i < 16; ++i) cnt += (key[i] == prefix) ? 1 : 0;
  int inc = cnt;
#pragma unroll
  for (int off = 1; off < 64; off <<= 1) {
    int y = __shfl_up(inc, off);
    if (lane >= off) inc += y;
  }
  if (lane == 63) s_wave[wv] = inc;
  __syncthreads();
  int waveoff = 0;
  for (int w = 0; w < wv; ++w) waveoff += s_wave[w];
  int run = waveoff + inc - cnt;  // equal keys strictly before my first token

  float* mrow = mask + (size_t)b * T_TOKENS + tid * 16;
#pragma unroll
  for (int i = 0; i < 16; i += 4) {
    float4 m4;
    float mv[4];
#pragma unroll
    for (int j = 0; j < 4; ++j) {
      unsigned int kk = key[i + j];
      bool keep = (kk > prefix) || (kk == prefix && run < krem);
      run += (kk == prefix) ? 1 : 0;
      mv[j] = keep ? 1.0f : 0.0f;
    }
    m4.x = mv[0]; m4.y = mv[1]; m4.z = mv[2]; m4.w = mv[3];
    *reinterpret_cast<float4*>(mrow + i) = m4;
  }
}

extern "C" void kernel_launch(void* const* d_in, const int* in_sizes, int n_in,
                              void* d_out, int out_size, void* d_ws, size_t ws_size,
                              hipStream_t stream) {
  const float* hidden = (const float*)d_in[0];
  const float* keep_ratio = (const float*)d_in[1];
  const float* W = (const float*)d_in[2];
  const float* bptr = (const float*)d_in[3];

  const int B = in_sizes[1];
  const int n_tokens = in_sizes[0] / C_DIM;  // B*T = 32768

  float* out = (float*)d_out;
  float* mask = out;                       // output 0: [B, T] mask as 0/1 float
  float* scores = out + (size_t)n_tokens;  // output 1: [B, T] fp32 scores

  // 4 waves/block, 2 tokens/wave -> 8 tokens per block.
  const int blocks = n_tokens / 8;
  score_kernel<<<blocks, 256, 0, stream>>>(hidden, W, bptr, scores);
  topk_mask_kernel<<<B, 256, 0, stream>>>(keep_ratio, scores, mask);
}

// Round 6
// 49.530 us; speedup vs baseline: 9.4176x; 1.0734x over previous
//
#include <hip/hip_runtime.h>

#define C_DIM 2048
#define T_TOKENS 4096

typedef float v4f __attribute__((ext_vector_type(4)));

// Kernel 1: scores[n] = dot(hidden[n, :], W) + b0, one wave per token
// (round-2 structure, validated at 49.4us total). Change vs round 2: four
// independent f64 accumulator chains (per vector component) to cut the
// serial f64 dependency from 32 to 8 FMA deep. Numerics: every product is
// still cvt_f64 x2 + fma_f64 (exact operands); only f64 summation order
// changes (~1e-16), far below any f32-key gap -> rank semantics unchanged.
__global__ __launch_bounds__(256) void score_kernel(
    const float* __restrict__ hidden, const float* __restrict__ W,
    const float* __restrict__ bptr, float* __restrict__ scores, int n_tokens) {
  const int wave = (int)((blockIdx.x * blockDim.x + threadIdx.x) >> 6);
  const int lane = threadIdx.x & 63;
  if (wave >= n_tokens) return;
  const float* row = hidden + (size_t)wave * C_DIM;
  double ax = 0.0, ay = 0.0, az = 0.0, aw = 0.0;
#pragma unroll
  for (int it = 0; it < C_DIM / (64 * 4); ++it) {
    const int c = it * 256 + lane * 4;
    v4f h = *reinterpret_cast<const v4f*>(row + c);
    v4f w = *reinterpret_cast<const v4f*>(W + c);
    ax += (double)h.x * (double)w.x;
    ay += (double)h.y * (double)w.y;
    az += (double)h.z * (double)w.z;
    aw += (double)h.w * (double)w.w;
  }
  double acc = (ax + ay) + (az + aw);
  for (int o = 32; o; o >>= 1) acc += __shfl_xor(acc, o);
  if (lane == 0) scores[wave] = (float)(acc + (double)bptr[0]);
}

// Kernel 2: per-batch variable-k top-k mask via 8-bit radix histogram descent
// (validated round 2, unchanged). Thread tid owns tokens [tid*16, tid*16+16);
// stable tie-break (smaller index first) matches argsort(argsort) rank.
__global__ __launch_bounds__(256) void topk_mask_kernel(
    const float* __restrict__ keep_ratio, const float* __restrict__ scores_all,
    float* __restrict__ mask) {
  const int b = blockIdx.x;
  const float* scores = scores_all + (size_t)b * T_TOKENS;
  __shared__ int s_hist[256];
  __shared__ int s_wave[4];
  __shared__ unsigned int s_sel;
  __shared__ int s_krem;
  const int tid = threadIdx.x;
  const int lane = tid & 63;
  const int wv = tid >> 6;

  // k = max(1, trunc(clip(kr, 0.1, 1.0) * T)); *4096 is a pure exponent
  // shift in fp32 -> exact, truncation matches jnp int32 cast bit-for-bit.
  float kf = fminf(fmaxf(keep_ratio[b], 0.1f), 1.0f);
  int k = (int)(kf * (float)T_TOKENS);
  if (k < 1) k = 1;

  // Load 16 contiguous scores -> order-preserving uint keys.
  unsigned int key[16];
  const float* base = scores + tid * 16;
#pragma unroll
  for (int i = 0; i < 16; i += 4) {
    float4 s4 = *reinterpret_cast<const float4*>(base + i);
    float ss[4] = {s4.x, s4.y, s4.z, s4.w};
#pragma unroll
    for (int j = 0; j < 4; ++j) {
      unsigned int u = __float_as_uint(ss[j]);
      key[i + j] = (u & 0x80000000u) ? ~u : (u | 0x80000000u);
    }
  }

  // 4-round byte radix descent: after round r, prefix = top (r+1) bytes of
  // the k-th largest key; krem = remaining quota within that prefix.
  unsigned int prefix = 0u;
  int krem = k;
#pragma unroll
  for (int round = 0; round < 4; ++round) {
    const int shift = 24 - 8 * round;
    const unsigned int pmask = (round == 0) ? 0u : (0xFFFFFFFFu << (shift + 8));

    s_hist[tid] = 0;
    __syncthreads();
#pragma unroll
    for (int i = 0; i < 16; ++i) {
      if ((key[i] & pmask) == prefix)
        atomicAdd(&s_hist[(key[i] >> shift) & 255], 1);
    }
    __syncthreads();

    // Inclusive suffix sum over 256 bins (bin index == tid).
    int v = s_hist[tid];
    int x = v;
#pragma unroll
    for (int off = 1; off < 64; off <<= 1) {
      int y = __shfl_down(x, off);
      if (lane + off < 64) x += y;
    }
    if (lane == 0) s_wave[wv] = x;
    __syncthreads();
    int add = 0;
    for (int w = wv + 1; w < 4; ++w) add += s_wave[w];
    const int suffix_incl = x + add;         // active keys in bins >= tid
    const int suffix_excl = suffix_incl - v; // bins > tid
    if (suffix_excl < krem && suffix_incl >= krem) {  // unique crossing bin
      s_sel = (unsigned int)tid;
      s_krem = krem - suffix_excl;
    }
    __syncthreads();
    prefix |= (s_sel << shift);
    krem = s_krem;
    __syncthreads();
  }
  // prefix = key of k-th largest; krem = # ties (by index order) to keep.

  // Stable tie-break: exclusive count of equal keys at smaller token index.
  int cnt = 0;
#pragma unroll
  for (int i = 0; i < 16; ++i) cnt += (key[i] == prefix) ? 1 : 0;
  int inc = cnt;
#pragma unroll
  for (int off = 1; off < 64; off <<= 1) {
    int y = __shfl_up(inc, off);
    if (lane >= off) inc += y;
  }
  if (lane == 63) s_wave[wv] = inc;
  __syncthreads();
  int waveoff = 0;
  for (int w = 0; w < wv; ++w) waveoff += s_wave[w];
  int run = waveoff + inc - cnt;  // equal keys strictly before my first token

  float* mrow = mask + (size_t)b * T_TOKENS + tid * 16;
#pragma unroll
  for (int i = 0; i < 16; i += 4) {
    float4 m4;
    float mv[4];
#pragma unroll
    for (int j = 0; j < 4; ++j) {
      unsigned int kk = key[i + j];
      bool keep = (kk > prefix) || (kk == prefix && run < krem);
      run += (kk == prefix) ? 1 : 0;
      mv[j] = keep ? 1.0f : 0.0f;
    }
    m4.x = mv[0]; m4.y = mv[1]; m4.z = mv[2]; m4.w = mv[3];
    *reinterpret_cast<float4*>(mrow + i) = m4;
  }
}

extern "C" void kernel_launch(void* const* d_in, const int* in_sizes, int n_in,
                              void* d_out, int out_size, void* d_ws, size_t ws_size,
                              hipStream_t stream) {
  const float* hidden = (const float*)d_in[0];
  const float* keep_ratio = (const float*)d_in[1];
  const float* W = (const float*)d_in[2];
  const float* bptr = (const float*)d_in[3];

  const int B = in_sizes[1];
  const int n_tokens = in_sizes[0] / C_DIM;  // B*T = 32768

  float* out = (float*)d_out;
  float* mask = out;                       // output 0: [B, T] mask as 0/1 float
  float* scores = out + (size_t)n_tokens;  // output 1: [B, T] fp32 scores

  // 4 waves/block, 1 token/wave (round-2 structure).
  const int blocks = (n_tokens + 3) / 4;
  score_kernel<<<blocks, 256, 0, stream>>>(hidden, W, bptr, scores, n_tokens);
  topk_mask_kernel<<<B, 256, 0, stream>>>(keep_ratio, scores, mask);
}